// Round 1
// baseline (327.627 us; speedup 1.0000x reference)
//
#include <hip/hip_runtime.h>
#include <stdint.h>

#define O_FEATS 28672
#define I_FEATS 8192
#define BATCH 8

typedef int i32x4 __attribute__((ext_vector_type(4)));

// ---------------------------------------------------------------------------
// Workspace layout (uint32 word indices into ws):
//   ws[0]        : final absmax (float bits, >= 1e-5), written by k_quant
//   ws[16..79]   : per-block absmax partials (64 blocks of k_absmax)
//   ws[128..191] : per-block sum_x partials, index = b*8 + seg
//   ws[1024..]   : x_q TRANSPOSED to MFMA-fragment order, 128 KB:
//                  T[S*1024 + L*16 + j] = x_q[row L&15][k=S*64+(L>>4)*16+j]
//                  (S = global K-step 0..127, L = lane 0..63; rows 8..15 = 0)
// ---------------------------------------------------------------------------

// Carry-free unpack of 4 ternary codes (bits [7:0] of p) to 4 unsigned bytes
// {c0,c1,c2,c3} at byte positions 0..3 == k-offsets 0..3 of that word.
static __device__ __forceinline__ int unpack4(uint32_t p) {
  uint32_t lo = p & 0x0Fu;
  uint32_t hi = (p >> 4) & 0x0Fu;
  uint32_t a = (lo * 0x41u) & 0x0303u;
  uint32_t b = (hi * 0x41u) & 0x0303u;
  return (int)(a | (b << 16));
}

// 64 blocks x 256 threads x 4 floats = 65536 elements; per-block partial max.
__global__ void k_absmax(const float* __restrict__ x, uint32_t* __restrict__ ws) {
  __shared__ float red[4];
  int t = threadIdx.x;
  float4 v = ((const float4*)x)[blockIdx.x * 256 + t];
  float m = fmaxf(fmaxf(fabsf(v.x), fabsf(v.y)), fmaxf(fabsf(v.z), fabsf(v.w)));
#pragma unroll
  for (int off = 32; off; off >>= 1)
    m = fmaxf(m, __shfl_xor(m, off));
  if ((t & 63) == 0) red[t >> 6] = m;
  __syncthreads();
  if (t == 0)
    ws[16 + blockIdx.x] =
        __float_as_uint(fmaxf(fmaxf(red[0], red[1]), fmaxf(red[2], red[3])));
}

// 128 blocks. Blocks 0..63: (b = blk>>3, seg = blk&7) quantize 1024 elems of
// row b, write into transposed layout T + partial sums. Blocks 64..127:
// zero-fill pad rows 8..15 of T.
__global__ void k_quant(const float* __restrict__ x, uint32_t* __restrict__ ws) {
  __shared__ float s_amax;
  __shared__ int reds[4];
  int t = threadIdx.x;
  if (blockIdx.x >= 64) {  // zero pad rows 8..15 in T
    int row = 8 + ((blockIdx.x - 64) >> 3), seg = blockIdx.x & 7;
    int k0 = seg * 1024 + t * 4;
    int S = k0 >> 6, g = (k0 >> 4) & 3, j = k0 & 15;
    ws[1024 + ((S * 1024 + (g * 16 + row) * 16 + j) >> 2)] = 0u;
    return;
  }
  int b = blockIdx.x >> 3, seg = blockIdx.x & 7;
  if (t < 64) {  // reduce the 64 absmax partials (redundantly per block)
    float m = __uint_as_float(ws[16 + t]);
#pragma unroll
    for (int off = 32; off; off >>= 1)
      m = fmaxf(m, __shfl_xor(m, off));
    if (t == 0) {
      float a = fmaxf(m, 1e-5f);
      s_amax = a;
      ws[0] = __float_as_uint(a);  // same value from every block: benign
    }
  }
  __syncthreads();
  float s = s_amax / 127.0f;  // match ref: x / (absmax/127)
  float4 v = ((const float4*)(x + b * I_FEATS + seg * 1024))[t];
  int q0 = (int)fminf(fmaxf(rintf(v.x / s), -128.f), 127.f);
  int q1 = (int)fminf(fmaxf(rintf(v.y / s), -128.f), 127.f);
  int q2 = (int)fminf(fmaxf(rintf(v.z / s), -128.f), 127.f);
  int q3 = (int)fminf(fmaxf(rintf(v.w / s), -128.f), 127.f);
  uint32_t pk = (uint32_t)(q0 & 0xff) | ((uint32_t)(q1 & 0xff) << 8) |
                ((uint32_t)(q2 & 0xff) << 16) | ((uint32_t)(q3 & 0xff) << 24);
  {  // scatter into transposed fragment layout (4 B words, aligned)
    int k0 = seg * 1024 + t * 4;
    int S = k0 >> 6, g = (k0 >> 4) & 3, j = k0 & 15;
    ws[1024 + ((S * 1024 + (g * 16 + b) * 16 + j) >> 2)] = pk;
  }
  int s4 = q0 + q1 + q2 + q3;
#pragma unroll
  for (int off = 32; off; off >>= 1)
    s4 += __shfl_xor(s4, off);
  if ((t & 63) == 0) reds[t >> 6] = s4;
  __syncthreads();
  if (t == 0)
    ws[128 + blockIdx.x] = (uint32_t)(reds[0] + reds[1] + reds[2] + reds[3]);
}

// MFMA GEMM, barrier-free direct streaming: 1792 blocks x 256 thr.
// Block -> 16 output rows; wave w owns the contiguous K-quarter
// codes [w*2048, (w+1)*2048) = 32 steps of K=64, in 8 groups of 4 steps.
// Per step, lane (m=lane&15, g=lane>>4):
//   B-frag = 16 B of row (o_base+m) at byte  w*2048 + step*64 + g*16
//            (global byte index == ternary code index), unpack4 per word.
//   A-frag = 16 B of transposed x_q at step S = w*32 + step, offset lane*16.
// Depth-2 register pipeline: while computing group gi, group gi+1's 8
// dwordx4 loads (8 KB/wave) are in flight -> no vmcnt(0) drain, no LDS,
// no __syncthreads in the main loop. Waves fully independent until the
// 4-way K-partial reduction epilogue.
// D layout: col(=output) = lane&15, row(=batch) = (lane>>4)*4 + reg.
__global__ void __launch_bounds__(256, 4)
k_gemm(const int* __restrict__ Wp, const float* __restrict__ wscale,
       const float* __restrict__ bias, const uint32_t* __restrict__ ws,
       float* __restrict__ out) {
  __shared__ int red[4][32][4];
  __shared__ int s_sumx[BATCH];
  __shared__ float s_scale;

  const int t = threadIdx.x;
  const int wave = t >> 6, lane = t & 63;
  const int m = lane & 15, g = lane >> 4;
  const int o_base = blockIdx.x * 16;

  // B: row (o_base+m), wave's K-quarter base, fragment sub-offset g*16.
  const uint8_t* bsrc = (const uint8_t*)Wp + (size_t)(o_base + m) * 8192 +
                        wave * 2048 + g * 16;
  // A: transposed x_q; global step S = wave*32 + local step.
  const uint8_t* asrc = (const uint8_t*)(ws + 1024) + (size_t)wave * 32768 +
                        lane * 16;

  if (t < 64) {  // reduce 64 sum_x partials: index = b*8+seg (wave 0 only)
    int p = (int)ws[128 + t];
    p += __shfl_xor(p, 1);
    p += __shfl_xor(p, 2);
    p += __shfl_xor(p, 4);
    if ((t & 7) == 0) s_sumx[t >> 3] = p;
    if (t == 0) s_scale = (__uint_as_float(ws[0]) / 127.0f) * wscale[0];
  }

  i32x4 acc = {0, 0, 0, 0};
  int4 bA[4], aA[4], bB[4], aB[4];

// Group gi = local steps 4*gi .. 4*gi+3. B offsets fit the 13-bit signed
// global-load immediate (max 8176); A offsets advance in 4 KB strides.
#define LOADG(gi, B, A)                                                   \
  do {                                                                    \
    const uint8_t* bp = bsrc + (gi) * 256;                                \
    const uint8_t* ap = asrc + (gi) * 4096;                               \
    B[0] = *(const int4*)(bp + 0);                                        \
    A[0] = *(const int4*)(ap + 0);                                        \
    B[1] = *(const int4*)(bp + 64);                                       \
    A[1] = *(const int4*)(ap + 1024);                                     \
    B[2] = *(const int4*)(bp + 128);                                      \
    A[2] = *(const int4*)(ap + 2048);                                     \
    B[3] = *(const int4*)(bp + 192);                                      \
    A[3] = *(const int4*)(ap + 3072);                                     \
  } while (0)

#define COMPG(B, A)                                                       \
  do {                                                                    \
    _Pragma("unroll") for (int s = 0; s < 4; ++s) {                       \
      i32x4 af, bf;                                                       \
      af.x = A[s].x;                                                      \
      af.y = A[s].y;                                                      \
      af.z = A[s].z;                                                      \
      af.w = A[s].w;                                                      \
      bf.x = unpack4((uint32_t)B[s].x);                                   \
      bf.y = unpack4((uint32_t)B[s].y);                                   \
      bf.z = unpack4((uint32_t)B[s].z);                                   \
      bf.w = unpack4((uint32_t)B[s].w);                                   \
      acc = __builtin_amdgcn_mfma_i32_16x16x64_i8(af, bf, acc, 0, 0, 0);  \
    }                                                                     \
  } while (0)

  // Depth-2 software pipeline over 8 groups, all indices compile-time.
  LOADG(0, bA, aA);
  LOADG(1, bB, aB);
  COMPG(bA, aA);
  LOADG(2, bA, aA);
  COMPG(bB, aB);
  LOADG(3, bB, aB);
  COMPG(bA, aA);
  LOADG(4, bA, aA);
  COMPG(bB, aB);
  LOADG(5, bB, aB);
  COMPG(bA, aA);
  LOADG(6, bA, aA);
  COMPG(bB, aB);
  LOADG(7, bB, aB);
  COMPG(bA, aA);
  COMPG(bB, aB);
#undef LOADG
#undef COMPG

  if (lane < 32) {  // batch rows 0..7 live in lanes 0..31
#pragma unroll
    for (int r = 0; r < 4; ++r) red[wave][lane][r] = acc[r];
  }
  __syncthreads();

  if (t < 32) {  // combine 4 wave-partials (disjoint K), epilogue, store
    const int n = t & 15;
    const int q = t >> 4;
    const int o = o_base + n;
    const float bo = bias[o];
#pragma unroll
    for (int r = 0; r < 4; ++r) {
      int mm = q * 4 + r;  // batch row 0..7
      int tot = red[0][t][r] + red[1][t][r] + red[2][t][r] + red[3][t][r];
      out[mm * O_FEATS + o] = (float)(tot - s_sumx[mm]) * s_scale + bo;
    }
  }
}

extern "C" void kernel_launch(void* const* d_in, const int* in_sizes, int n_in,
                              void* d_out, int out_size, void* d_ws, size_t ws_size,
                              hipStream_t stream) {
  const float* x = (const float*)d_in[0];
  const int* pw = (const int*)d_in[1];
  const float* wscale = (const float*)d_in[2];
  const float* bias = (const float*)d_in[3];
  float* out = (float*)d_out;
  uint32_t* ws = (uint32_t*)d_ws;

  k_absmax<<<64, 256, 0, stream>>>(x, ws);
  k_quant<<<128, 256, 0, stream>>>(x, ws);
  k_gemm<<<O_FEATS / 16, 256, 0, stream>>>(pw, wscale, bias, ws, out);
}

// Round 2
// 320.545 us; speedup vs baseline: 1.0221x; 1.0221x over previous
//
#include <hip/hip_runtime.h>
#include <stdint.h>

#define O_FEATS 28672
#define I_FEATS 8192
#define BATCH 8
#define PITCH_W 260  // LDS words per W row: 1024 B data + 16 B pad (bank stagger)

typedef int i32x4 __attribute__((ext_vector_type(4)));

// ---------------------------------------------------------------------------
// Workspace layout (uint32 word indices into ws):
//   ws[0]        : final absmax (float bits, >= 1e-5), written by k_quant
//   ws[16..79]   : per-block absmax partials (64 blocks of k_absmax)
//   ws[128..191] : per-block sum_x partials, index = b*8 + seg
//   ws[1024..]   : x_q TRANSPOSED to MFMA-fragment order, 128 KB:
//                  T[S*1024 + L*16 + j] = x_q[row L&15][k=S*64+(L>>4)*16+j]
//                  (S = global K-step 0..127, L = lane 0..63; rows 8..15 = 0)
// ---------------------------------------------------------------------------

// Carry-free unpack of 4 ternary codes (bits [7:0] of p) to 4 unsigned bytes
// {c0,c1,c2,c3} at byte positions 0..3 == k-offsets 0..3 of that word.
static __device__ __forceinline__ int unpack4(uint32_t p) {
  uint32_t lo = p & 0x0Fu;
  uint32_t hi = (p >> 4) & 0x0Fu;
  uint32_t a = (lo * 0x41u) & 0x0303u;
  uint32_t b = (hi * 0x41u) & 0x0303u;
  return (int)(a | (b << 16));
}

// 64 blocks x 256 threads x 4 floats = 65536 elements; per-block partial max.
__global__ void k_absmax(const float* __restrict__ x, uint32_t* __restrict__ ws) {
  __shared__ float red[4];
  int t = threadIdx.x;
  float4 v = ((const float4*)x)[blockIdx.x * 256 + t];
  float m = fmaxf(fmaxf(fabsf(v.x), fabsf(v.y)), fmaxf(fabsf(v.z), fabsf(v.w)));
#pragma unroll
  for (int off = 32; off; off >>= 1)
    m = fmaxf(m, __shfl_xor(m, off));
  if ((t & 63) == 0) red[t >> 6] = m;
  __syncthreads();
  if (t == 0)
    ws[16 + blockIdx.x] =
        __float_as_uint(fmaxf(fmaxf(red[0], red[1]), fmaxf(red[2], red[3])));
}

// 128 blocks. Blocks 0..63: (b = blk>>3, seg = blk&7) quantize 1024 elems of
// row b, write into transposed layout T + partial sums. Blocks 64..127:
// zero-fill pad rows 8..15 of T.
__global__ void k_quant(const float* __restrict__ x, uint32_t* __restrict__ ws) {
  __shared__ float s_amax;
  __shared__ int reds[4];
  int t = threadIdx.x;
  if (blockIdx.x >= 64) {  // zero pad rows 8..15 in T
    int row = 8 + ((blockIdx.x - 64) >> 3), seg = blockIdx.x & 7;
    int k0 = seg * 1024 + t * 4;
    int S = k0 >> 6, g = (k0 >> 4) & 3, j = k0 & 15;
    ws[1024 + ((S * 1024 + (g * 16 + row) * 16 + j) >> 2)] = 0u;
    return;
  }
  int b = blockIdx.x >> 3, seg = blockIdx.x & 7;
  if (t < 64) {  // reduce the 64 absmax partials (redundantly per block)
    float m = __uint_as_float(ws[16 + t]);
#pragma unroll
    for (int off = 32; off; off >>= 1)
      m = fmaxf(m, __shfl_xor(m, off));
    if (t == 0) {
      float a = fmaxf(m, 1e-5f);
      s_amax = a;
      ws[0] = __float_as_uint(a);  // same value from every block: benign
    }
  }
  __syncthreads();
  float s = s_amax / 127.0f;  // match ref: x / (absmax/127)
  float4 v = ((const float4*)(x + b * I_FEATS + seg * 1024))[t];
  int q0 = (int)fminf(fmaxf(rintf(v.x / s), -128.f), 127.f);
  int q1 = (int)fminf(fmaxf(rintf(v.y / s), -128.f), 127.f);
  int q2 = (int)fminf(fmaxf(rintf(v.z / s), -128.f), 127.f);
  int q3 = (int)fminf(fmaxf(rintf(v.w / s), -128.f), 127.f);
  uint32_t pk = (uint32_t)(q0 & 0xff) | ((uint32_t)(q1 & 0xff) << 8) |
                ((uint32_t)(q2 & 0xff) << 16) | ((uint32_t)(q3 & 0xff) << 24);
  {  // scatter into transposed fragment layout (4 B words, aligned)
    int k0 = seg * 1024 + t * 4;
    int S = k0 >> 6, g = (k0 >> 4) & 3, j = k0 & 15;
    ws[1024 + ((S * 1024 + (g * 16 + b) * 16 + j) >> 2)] = pk;
  }
  int s4 = q0 + q1 + q2 + q3;
#pragma unroll
  for (int off = 32; off; off >>= 1)
    s4 += __shfl_xor(s4, off);
  if ((t & 63) == 0) reds[t >> 6] = s4;
  __syncthreads();
  if (t == 0)
    ws[128 + blockIdx.x] = (uint32_t)(reds[0] + reds[1] + reds[2] + reds[3]);
}

// MFMA GEMM, 2-phase pipelined LDS staging: 1792 blocks x 256 thr.
// Block -> 16 output rows. K in 8 chunks of 1024 B/row, double-buffered LDS.
// Per chunk c (steady state):
//   1. issue stage(c+1): wave w async-copies rows w*4+i (i=0..3), bytes
//      [(c+1)*1024, +1024) via global_load_lds into buf[(c+1)&1].
//      Global source is lane-XOR-swizzled: lane L reads unit (L^i) of the
//      1 KB row (XOR only permutes within 64-B granules -> coalescing kept),
//      so LDS[row][u] = G[row][u ^ (row&3)]  (T2-via-pre-swizzled-source).
//   2. issue A-prefetch(c+1): 4 x dwordx4 from transposed x_q (contiguous
//      1 KB per instr, L2-resident) into the spare register quartet.
//   3. compute chunk c: wave w owns k-sub [w*256,(w+1)*256) = 4 steps of
//      K=64. B-frag read at word m*260 + w*64 + s*16 + (g^(m&3))*4 (the
//      XOR undone; 260-word pitch -> 8 lanes per 4-bank group = conflict-
//      free); unpack4 -> MFMA i32_16x16x64.
//   4. __syncthreads(): its vmcnt(0) drain lands AFTER ~400 cy of compute
//      has covered most of stage(c+1)'s HBM latency (vs R0 which drained
//      immediately after issue -> full latency exposed every chunk).
// D layout: col(=output) = lane&15, row(=batch) = (lane>>4)*4 + reg.
__global__ void __launch_bounds__(256, 4)
k_gemm(const int* __restrict__ Wp, const float* __restrict__ wscale,
       const float* __restrict__ bias, const uint32_t* __restrict__ ws,
       float* __restrict__ out) {
  __shared__ uint32_t Wlds[2][16 * PITCH_W];  // 2 x 16.6 KB staged W chunks
  __shared__ int red[4][32][4];
  __shared__ int s_sumx[BATCH];
  __shared__ float s_scale;

  const int t = threadIdx.x;
  const int wave = t >> 6, lane = t & 63;
  const int m = lane & 15, g = lane >> 4;
  const int o_base = blockIdx.x * 16;

  if (t < 64) {  // reduce 64 sum_x partials: index = b*8+seg
    int p = (int)ws[128 + t];
    p += __shfl_xor(p, 1);
    p += __shfl_xor(p, 2);
    p += __shfl_xor(p, 4);
    if ((t & 7) == 0) s_sumx[t >> 3] = p;
    if (t == 0) s_scale = (__uint_as_float(ws[0]) / 127.0f) * wscale[0];
  }

  // A: transposed x_q; step S = c*16 + wave*4 + s (wave*4 folded into base).
  const uint8_t* asrc =
      (const uint8_t*)(ws + 1024) + (size_t)(wave * 4) * 1024 + lane * 16;

  // B staging: rows (o_base + wave*4 + i), chunk offset c*1024, lane-swizzled.
  const uint8_t* wrow_base =
      (const uint8_t*)Wp + (size_t)(o_base + wave * 4) * 8192;
  uint32_t* lds_w0 = &Wlds[0][(wave * 4) * PITCH_W];
  uint32_t* lds_w1 = &Wlds[1][(wave * 4) * PITCH_W];

  // B fragment read base (word index); + s*16 words per step.
  const int bword = m * PITCH_W + wave * 64 + ((g ^ (m & 3)) << 2);
  const uint32_t* bp0 = &Wlds[0][bword];
  const uint32_t* bp1 = &Wlds[1][bword];

#define STAGE(c, dst)                                                        \
  do {                                                                       \
    _Pragma("unroll") for (int i = 0; i < 4; ++i) {                          \
      const uint32_t* src = (const uint32_t*)(wrow_base + (size_t)i * 8192 + \
                                              (c) * 1024 + ((lane ^ i) << 4)); \
      __builtin_amdgcn_global_load_lds(src, (dst) + i * PITCH_W, 16, 0, 0);  \
    }                                                                        \
  } while (0)

  i32x4 acc = {0, 0, 0, 0};
  int4 aA[4], aB[4];

  // Prologue: stage + A-load chunk 0 (full drain, once).
  STAGE(0, lds_w0);
#pragma unroll
  for (int s = 0; s < 4; ++s)
    aA[s] = *(const int4*)(asrc + (size_t)s * 1024);
  __syncthreads();

#pragma unroll
  for (int c = 0; c < 8; ++c) {
    if (c < 7) {  // issue next chunk's stage + A-prefetch FIRST (overlap)
      STAGE(c + 1, (c & 1) ? lds_w0 : lds_w1);
      int4* an = (c & 1) ? aA : aB;
#pragma unroll
      for (int s = 0; s < 4; ++s)
        an[s] = *(const int4*)(asrc + (size_t)((c + 1) * 16 + s) * 1024);
    }
    const uint32_t* bp = (c & 1) ? bp1 : bp0;
    const int4* A = (c & 1) ? aB : aA;
#pragma unroll
    for (int s = 0; s < 4; ++s) {
      int4 b = *(const int4*)(bp + s * 16);
      i32x4 af, bf;
      af.x = A[s].x;
      af.y = A[s].y;
      af.z = A[s].z;
      af.w = A[s].w;
      bf.x = unpack4((uint32_t)b.x);
      bf.y = unpack4((uint32_t)b.y);
      bf.z = unpack4((uint32_t)b.z);
      bf.w = unpack4((uint32_t)b.w);
      acc = __builtin_amdgcn_mfma_i32_16x16x64_i8(af, bf, acc, 0, 0, 0);
    }
    __syncthreads();  // vmcnt(0)+lgkmcnt(0)+barrier: stage(c+1) now visible
  }
#undef STAGE

  if (lane < 32) {  // batch rows 0..7 live in lanes 0..31
#pragma unroll
    for (int r = 0; r < 4; ++r) red[wave][lane][r] = acc[r];
  }
  __syncthreads();

  if (t < 32) {  // combine 4 wave-partials (disjoint K), epilogue, store
    const int n = t & 15;
    const int q = t >> 4;
    const int o = o_base + n;
    const float bo = bias[o];
#pragma unroll
    for (int r = 0; r < 4; ++r) {
      int mm = q * 4 + r;  // batch row 0..7
      int tot = red[0][t][r] + red[1][t][r] + red[2][t][r] + red[3][t][r];
      out[mm * O_FEATS + o] = (float)(tot - s_sumx[mm]) * s_scale + bo;
    }
  }
}

extern "C" void kernel_launch(void* const* d_in, const int* in_sizes, int n_in,
                              void* d_out, int out_size, void* d_ws, size_t ws_size,
                              hipStream_t stream) {
  const float* x = (const float*)d_in[0];
  const int* pw = (const int*)d_in[1];
  const float* wscale = (const float*)d_in[2];
  const float* bias = (const float*)d_in[3];
  float* out = (float*)d_out;
  uint32_t* ws = (uint32_t*)d_ws;

  k_absmax<<<64, 256, 0, stream>>>(x, ws);
  k_quant<<<128, 256, 0, stream>>>(x, ws);
  k_gemm<<<O_FEATS / 16, 256, 0, stream>>>(pw, wscale, bias, ws, out);
}